// Round 1
// baseline (79.294 us; speedup 1.0000x reference)
//
#include <hip/hip_runtime.h>
#include <math.h>

#define H 1024
#define W 1024
#define OH 1016
#define OW 1016
#define TILE 32
#define IN_T 40      // input tile rows/cols (32 + 8 halo)
#define DXT 36       // dx tile rows/cols (32 + 4 halo)
#define STR 44       // LDS row stride in floats (44*4=176 B, 16B aligned)

// LDS float offsets
#define SX 0
#define SY (IN_T*STR)             // 1760
#define CA (2*IN_T*STR)           // 3520
#define CB (CA + DXT*STR)         // 5104
#define P1 (CB + DXT*STR)         // 6688
#define P2 (P1 + DXT*STR)         // 8272
#define P3 (P2 + DXT*STR)         // 9856
#define LDS_FLOATS (P3 + DXT*STR) // 11440  (45.76 KB)
// c1..c3 alias the dead sx/sy/ca region after phase 3
#define C1 0
#define C2 (TILE*STR)             // 1408
#define C3 (2*TILE*STR)           // 2816  (ends 4224 < 6688, safe)

#define EPS 1e-6f
#define INV25 (1.0f/25.0f)

__device__ __forceinline__ float4 ld4s(const float* p) { return *reinterpret_cast<const float4*>(p); }
__device__ __forceinline__ void st4s(float* p, float4 v) { *reinterpret_cast<float4*>(p) = v; }
__device__ __forceinline__ float4 add4(float4 a, float4 b) {
    return make_float4(a.x + b.x, a.y + b.y, a.z + b.z, a.w + b.w);
}

__global__ __launch_bounds__(256)
void yiq_gngc_fused(const float* __restrict__ x, const float* __restrict__ y,
                    float* __restrict__ out, long long Nper) {
    __shared__ __align__(16) float lds[LDS_FLOATS];
    const int tid = threadIdx.x;
    const int ox = blockIdx.x * TILE;
    const int oy = blockIdx.y * TILE;
    const int b  = blockIdx.z;
    const float* xb = x + (size_t)b * (H * W);
    const float* yb = y + (size_t)b * (H * W);

    // ---------- Phase 1: load 40x40 halo tiles of x,y into LDS ----------
    if (ox + IN_T <= W) {
        // interior columns: float4 global loads (rows clamped for bottom tiles)
        for (int idx = tid; idx < IN_T * 10; idx += 256) {
            int r = idx / 10, c4 = (idx % 10) * 4;
            int gr = oy + r; if (gr > H - 1) gr = H - 1;
            const size_t g = (size_t)gr * W + ox + c4;
            st4s(&lds[SX + r * STR + c4], ld4s(xb + g));
            st4s(&lds[SY + r * STR + c4], ld4s(yb + g));
        }
    } else {
        // right-edge tiles: scalar clamped loads
        for (int idx = tid; idx < IN_T * IN_T; idx += 256) {
            int r = idx / IN_T, c = idx % IN_T;
            int gr = oy + r; if (gr > H - 1) gr = H - 1;
            int gc = ox + c; if (gc > W - 1) gc = W - 1;
            const size_t g = (size_t)gr * W + gc;
            lds[SX + r * STR + c] = xb[g];
            lds[SY + r * STR + c] = yb[g];
        }
    }
    __syncthreads();

    // ---------- Phase 2: stage-A column sums (5 rows) -> ca, cb ----------
    // 36 rows x 10 col-groups x 2 arrays = 720 tasks
    for (int idx = tid; idx < 2 * DXT * 10; idx += 256) {
        int arr = idx / (DXT * 10);
        int rem = idx % (DXT * 10);
        int r = rem / 10, c4 = (rem % 10) * 4;
        int src = (arr ? SY : SX) + r * STR + c4;
        float4 s = ld4s(&lds[src]);
        s = add4(s, ld4s(&lds[src + 1 * STR]));
        s = add4(s, ld4s(&lds[src + 2 * STR]));
        s = add4(s, ld4s(&lds[src + 3 * STR]));
        s = add4(s, ld4s(&lds[src + 4 * STR]));
        st4s(&lds[(arr ? CB : CA) + r * STR + c4], s);
    }
    __syncthreads();

    // ---------- Phase 3: dx,dy + products -> p1,p2,p3 ----------
    // 36 rows x 9 col-groups = 324 tasks (cols 0..35)
    for (int idx = tid; idx < DXT * 9; idx += 256) {
        int r = idx / 9, c4 = (idx % 9) * 4;
        const int rowA = r * STR + c4;
        float4 a0 = ld4s(&lds[CA + rowA]);
        float4 a1 = ld4s(&lds[CA + rowA + 4]);
        float4 b0 = ld4s(&lds[CB + rowA]);
        float4 b1 = ld4s(&lds[CB + rowA + 4]);
        const int rowC = (r + 2) * STR + c4;
        float4 cx0 = ld4s(&lds[SX + rowC]);
        float4 cx1 = ld4s(&lds[SX + rowC + 4]);
        float4 cy0 = ld4s(&lds[SY + rowC]);
        float4 cy1 = ld4s(&lds[SY + rowC + 4]);
        float a[8]  = {a0.x, a0.y, a0.z, a0.w, a1.x, a1.y, a1.z, a1.w};
        float bb[8] = {b0.x, b0.y, b0.z, b0.w, b1.x, b1.y, b1.z, b1.w};
        float cx[8] = {cx0.x, cx0.y, cx0.z, cx0.w, cx1.x, cx1.y, cx1.z, cx1.w};
        float cy[8] = {cy0.x, cy0.y, cy0.z, cy0.w, cy1.x, cy1.y, cy1.z, cy1.w};
        float dx[4], dy[4];
        #pragma unroll
        for (int t = 0; t < 4; ++t) {
            float mx = (a[t] + a[t+1] + a[t+2] + a[t+3] + a[t+4]) * INV25;
            float my = (bb[t] + bb[t+1] + bb[t+2] + bb[t+3] + bb[t+4]) * INV25;
            dx[t] = cx[t + 2] - mx;
            dy[t] = cy[t + 2] - my;
        }
        st4s(&lds[P1 + rowA], make_float4(dx[0]*dy[0], dx[1]*dy[1], dx[2]*dy[2], dx[3]*dy[3]));
        st4s(&lds[P2 + rowA], make_float4(dx[0]*dx[0], dx[1]*dx[1], dx[2]*dx[2], dx[3]*dx[3]));
        st4s(&lds[P3 + rowA], make_float4(dy[0]*dy[0], dy[1]*dy[1], dy[2]*dy[2], dy[3]*dy[3]));
    }
    __syncthreads();

    // ---------- Phase 4: stage-B column sums -> c1,c2,c3 ----------
    // 32 rows x 9 col-groups x 3 arrays = 864 tasks
    for (int idx = tid; idx < 3 * TILE * 9; idx += 256) {
        int arr = idx / (TILE * 9);
        int rem = idx % (TILE * 9);
        int r = rem / 9, c4 = (rem % 9) * 4;
        int src = P1 + arr * (DXT * STR) + r * STR + c4;  // P1,P2,P3 contiguous
        float4 s = ld4s(&lds[src]);
        s = add4(s, ld4s(&lds[src + 1 * STR]));
        s = add4(s, ld4s(&lds[src + 2 * STR]));
        s = add4(s, ld4s(&lds[src + 3 * STR]));
        s = add4(s, ld4s(&lds[src + 4 * STR]));
        st4s(&lds[C1 + arr * (TILE * STR) + r * STR + c4], s);
    }
    __syncthreads();

    // ---------- Phase 5: row sums + finalize + store ----------
    // 32 rows x 8 col-groups = 256 tasks: exactly one per thread
    {
        int r = tid / 8, c4 = (tid % 8) * 4;
        const int row = r * STR + c4;
        float4 u0 = ld4s(&lds[C1 + row]);
        float4 u1 = ld4s(&lds[C1 + row + 4]);
        float4 v0 = ld4s(&lds[C2 + row]);
        float4 v1 = ld4s(&lds[C2 + row + 4]);
        float4 w0 = ld4s(&lds[C3 + row]);
        float4 w1 = ld4s(&lds[C3 + row + 4]);
        float s1[8] = {u0.x, u0.y, u0.z, u0.w, u1.x, u1.y, u1.z, u1.w};
        float s2[8] = {v0.x, v0.y, v0.z, v0.w, v1.x, v1.y, v1.z, v1.w};
        float s3[8] = {w0.x, w0.y, w0.z, w0.w, w1.x, w1.y, w1.z, w1.w};
        float corr[4], vvv[4], cc[4];
        #pragma unroll
        for (int t = 0; t < 4; ++t) {
            float c_  = (s1[t] + s1[t+1] + s1[t+2] + s1[t+3] + s1[t+4]) * INV25;
            float vx  = (s2[t] + s2[t+1] + s2[t+2] + s2[t+3] + s2[t+4]) * INV25;
            float vy  = (s3[t] + s3[t+1] + s3[t+2] + s3[t+3] + s3[t+4]) * INV25;
            float vv  = sqrtf(vx * vy);
            bool low  = vv < EPS;
            float cv  = low ? 0.0f : c_;
            float vvs = low ? EPS : vv;
            float r_  = cv / vvs;
            r_ = r_ < 0.0f ? 0.0f : (r_ > 1.0f ? 1.0f : r_);
            corr[t] = r_; vvv[t] = vvs; cc[t] = cv;
        }
        int i = oy + r;
        int j0 = ox + c4;
        if (i < OH) {
            float* o = out + (size_t)b * (OH * OW) + (size_t)i * OW + j0;
            if (j0 + 3 < OW) {
                st4s(o,                make_float4(corr[0], corr[1], corr[2], corr[3]));
                st4s(o + Nper,        make_float4(vvv[0],  vvv[1],  vvv[2],  vvv[3]));
                st4s(o + 2 * Nper,    make_float4(cc[0],   cc[1],   cc[2],   cc[3]));
            } else {
                #pragma unroll
                for (int t = 0; t < 4; ++t) {
                    if (j0 + t < OW) {
                        o[t] = corr[t];
                        o[t + Nper] = vvv[t];
                        o[t + 2 * Nper] = cc[t];
                    }
                }
            }
        }
    }
}

extern "C" void kernel_launch(void* const* d_in, const int* in_sizes, int n_in,
                              void* d_out, int out_size, void* d_ws, size_t ws_size,
                              hipStream_t stream) {
    const float* x = (const float*)d_in[0];
    const float* y = (const float*)d_in[1];
    // mask (d_in[2]) is unused by the reference's channels==1 path
    float* out = (float*)d_out;
    const int B = in_sizes[0] / (H * W);
    const long long Nper = (long long)out_size / 3;  // elements per output array
    dim3 grid((OW + TILE - 1) / TILE, (OH + TILE - 1) / TILE, B);
    yiq_gngc_fused<<<grid, dim3(256), 0, stream>>>(x, y, out, Nper);
}

// Round 2
// 66.763 us; speedup vs baseline: 1.1877x; 1.1877x over previous
//
#include <hip/hip_runtime.h>
#include <math.h>

#define H 1024
#define W 1024
#define OH 1016
#define OW 1016
#define TILE 32
#define IN_T 40      // input tile rows/cols (32 + 8 halo)
#define DXT 36       // dx tile rows/cols (32 + 4 halo)
#define STRI 40      // stride for input + stage-A colsum tiles (contiguous, 10 groups)
#define STRP 36      // stride for product + stage-B tiles (contiguous, 9 groups)

// LDS float offsets (total 9968 floats = 39872 B -> 4 blocks/CU)
#define SX 0
#define SY (IN_T*STRI)              // 1600
#define CA (2*IN_T*STRI)            // 3200
#define CB (CA + DXT*STRI)          // 4640
#define P1 (CB + DXT*STRI)          // 6080
#define P2 (P1 + DXT*STRP)          // 7376
#define P3 (P2 + DXT*STRP)          // 8672
#define LDS_FLOATS (P3 + DXT*STRP)  // 9968
// c1..c3 alias the dead sx/sy region after phase 3 (3*1152 = 3456 < 6080)
#define C1 0
#define C2 (TILE*STRP)              // 1152
#define C3 (2*TILE*STRP)            // 2304

#define EPS 1e-6f
#define INV25 (1.0f/25.0f)

__device__ __forceinline__ float4 ld4s(const float* p) { return *reinterpret_cast<const float4*>(p); }
__device__ __forceinline__ void st4s(float* p, float4 v) { *reinterpret_cast<float4*>(p) = v; }
__device__ __forceinline__ float4 add4(float4 a, float4 b) {
    return make_float4(a.x + b.x, a.y + b.y, a.z + b.z, a.w + b.w);
}

__global__ __launch_bounds__(256)
void yiq_gngc_fused(const float* __restrict__ x, const float* __restrict__ y,
                    float* __restrict__ out, long long Nper) {
    __shared__ __align__(16) float lds[LDS_FLOATS];
    const int tid = threadIdx.x;
    const int ox = blockIdx.x * TILE;
    const int oy = blockIdx.y * TILE;
    const int b  = blockIdx.z;
    const float* xb = x + (size_t)b * (H * W);
    const float* yb = y + (size_t)b * (H * W);

    // ---------- Phase 1: load 40x40 halo tiles of x,y into LDS ----------
    if (ox + IN_T <= W) {
        // interior columns: float4 global loads (rows clamped for bottom tiles)
        for (int idx = tid; idx < IN_T * 10; idx += 256) {
            int r = idx / 10, c4 = (idx % 10) * 4;
            int gr = oy + r; if (gr > H - 1) gr = H - 1;
            const size_t g = (size_t)gr * W + ox + c4;
            st4s(&lds[SX + r * STRI + c4], ld4s(xb + g));
            st4s(&lds[SY + r * STRI + c4], ld4s(yb + g));
        }
    } else {
        // right-edge tiles: scalar clamped loads
        for (int idx = tid; idx < IN_T * IN_T; idx += 256) {
            int r = idx / IN_T, c = idx % IN_T;
            int gr = oy + r; if (gr > H - 1) gr = H - 1;
            int gc = ox + c; if (gc > W - 1) gc = W - 1;
            const size_t g = (size_t)gr * W + gc;
            lds[SX + r * STRI + c] = xb[g];
            lds[SY + r * STRI + c] = yb[g];
        }
    }
    __syncthreads();

    // ---------- Phase 2: stage-A column sums (5 rows) -> ca, cb ----------
    // 36 rows x 10 col-groups x 2 arrays = 720 tasks; lane addresses contiguous
    for (int idx = tid; idx < 2 * DXT * 10; idx += 256) {
        int arr = idx / (DXT * 10);
        int rem = idx % (DXT * 10);
        int r = rem / 10, c4 = (rem % 10) * 4;
        int src = (arr ? SY : SX) + r * STRI + c4;
        float4 s = ld4s(&lds[src]);
        s = add4(s, ld4s(&lds[src + 1 * STRI]));
        s = add4(s, ld4s(&lds[src + 2 * STRI]));
        s = add4(s, ld4s(&lds[src + 3 * STRI]));
        s = add4(s, ld4s(&lds[src + 4 * STRI]));
        st4s(&lds[(arr ? CB : CA) + r * STRI + c4], s);
    }
    __syncthreads();

    // ---------- Phase 3: dx,dy + products -> p1,p2,p3 ----------
    // 36 rows x 9 col-groups = 324 tasks (cols 0..35)
    for (int idx = tid; idx < DXT * 9; idx += 256) {
        int r = idx / 9, c4 = (idx % 9) * 4;
        const int rowA = r * STRI + c4;
        float4 a0 = ld4s(&lds[CA + rowA]);
        float4 a1 = ld4s(&lds[CA + rowA + 4]);
        float4 b0 = ld4s(&lds[CB + rowA]);
        float4 b1 = ld4s(&lds[CB + rowA + 4]);
        const int rowC = (r + 2) * STRI + c4;
        float4 cx0 = ld4s(&lds[SX + rowC]);
        float4 cx1 = ld4s(&lds[SX + rowC + 4]);
        float4 cy0 = ld4s(&lds[SY + rowC]);
        float4 cy1 = ld4s(&lds[SY + rowC + 4]);
        float a[8]  = {a0.x, a0.y, a0.z, a0.w, a1.x, a1.y, a1.z, a1.w};
        float bb[8] = {b0.x, b0.y, b0.z, b0.w, b1.x, b1.y, b1.z, b1.w};
        float cx[8] = {cx0.x, cx0.y, cx0.z, cx0.w, cx1.x, cx1.y, cx1.z, cx1.w};
        float cy[8] = {cy0.x, cy0.y, cy0.z, cy0.w, cy1.x, cy1.y, cy1.z, cy1.w};
        float dx[4], dy[4];
        #pragma unroll
        for (int t = 0; t < 4; ++t) {
            float mx = (a[t] + a[t+1] + a[t+2] + a[t+3] + a[t+4]) * INV25;
            float my = (bb[t] + bb[t+1] + bb[t+2] + bb[t+3] + bb[t+4]) * INV25;
            dx[t] = cx[t + 2] - mx;
            dy[t] = cy[t + 2] - my;
        }
        const int rowP = r * STRP + c4;
        st4s(&lds[P1 + rowP], make_float4(dx[0]*dy[0], dx[1]*dy[1], dx[2]*dy[2], dx[3]*dy[3]));
        st4s(&lds[P2 + rowP], make_float4(dx[0]*dx[0], dx[1]*dx[1], dx[2]*dx[2], dx[3]*dx[3]));
        st4s(&lds[P3 + rowP], make_float4(dy[0]*dy[0], dy[1]*dy[1], dy[2]*dy[2], dy[3]*dy[3]));
    }
    __syncthreads();

    // ---------- Phase 4: stage-B column sums -> c1,c2,c3 ----------
    // 32 rows x 9 col-groups x 3 arrays = 864 tasks; lane addresses contiguous
    for (int idx = tid; idx < 3 * TILE * 9; idx += 256) {
        int arr = idx / (TILE * 9);
        int rem = idx % (TILE * 9);
        int r = rem / 9, c4 = (rem % 9) * 4;
        int src = P1 + arr * (DXT * STRP) + r * STRP + c4;  // P1,P2,P3 contiguous
        float4 s = ld4s(&lds[src]);
        s = add4(s, ld4s(&lds[src + 1 * STRP]));
        s = add4(s, ld4s(&lds[src + 2 * STRP]));
        s = add4(s, ld4s(&lds[src + 3 * STRP]));
        s = add4(s, ld4s(&lds[src + 4 * STRP]));
        st4s(&lds[C1 + arr * (TILE * STRP) + r * STRP + c4], s);
    }
    __syncthreads();

    // ---------- Phase 5: row sums + finalize + store ----------
    // 32 rows x 8 col-groups = 256 tasks: exactly one per thread
    {
        int r = tid / 8, c4 = (tid % 8) * 4;
        const int row = r * STRP + c4;
        float4 u0 = ld4s(&lds[C1 + row]);
        float4 u1 = ld4s(&lds[C1 + row + 4]);
        float4 v0 = ld4s(&lds[C2 + row]);
        float4 v1 = ld4s(&lds[C2 + row + 4]);
        float4 w0 = ld4s(&lds[C3 + row]);
        float4 w1 = ld4s(&lds[C3 + row + 4]);
        float s1[8] = {u0.x, u0.y, u0.z, u0.w, u1.x, u1.y, u1.z, u1.w};
        float s2[8] = {v0.x, v0.y, v0.z, v0.w, v1.x, v1.y, v1.z, v1.w};
        float s3[8] = {w0.x, w0.y, w0.z, w0.w, w1.x, w1.y, w1.z, w1.w};
        float corr[4], vvv[4], cc[4];
        #pragma unroll
        for (int t = 0; t < 4; ++t) {
            float c_  = (s1[t] + s1[t+1] + s1[t+2] + s1[t+3] + s1[t+4]) * INV25;
            float vx  = (s2[t] + s2[t+1] + s2[t+2] + s2[t+3] + s2[t+4]) * INV25;
            float vy  = (s3[t] + s3[t+1] + s3[t+2] + s3[t+3] + s3[t+4]) * INV25;
            float vv  = sqrtf(vx * vy);
            bool low  = vv < EPS;
            float cv  = low ? 0.0f : c_;
            float vvs = low ? EPS : vv;
            float r_  = cv / vvs;
            r_ = r_ < 0.0f ? 0.0f : (r_ > 1.0f ? 1.0f : r_);
            corr[t] = r_; vvv[t] = vvs; cc[t] = cv;
        }
        int i = oy + r;
        int j0 = ox + c4;
        if (i < OH) {
            float* o = out + (size_t)b * (OH * OW) + (size_t)i * OW + j0;
            if (j0 + 3 < OW) {
                st4s(o,                make_float4(corr[0], corr[1], corr[2], corr[3]));
                st4s(o + Nper,        make_float4(vvv[0],  vvv[1],  vvv[2],  vvv[3]));
                st4s(o + 2 * Nper,    make_float4(cc[0],   cc[1],   cc[2],   cc[3]));
            } else {
                #pragma unroll
                for (int t = 0; t < 4; ++t) {
                    if (j0 + t < OW) {
                        o[t] = corr[t];
                        o[t + Nper] = vvv[t];
                        o[t + 2 * Nper] = cc[t];
                    }
                }
            }
        }
    }
}

extern "C" void kernel_launch(void* const* d_in, const int* in_sizes, int n_in,
                              void* d_out, int out_size, void* d_ws, size_t ws_size,
                              hipStream_t stream) {
    const float* x = (const float*)d_in[0];
    const float* y = (const float*)d_in[1];
    // mask (d_in[2]) is unused by the reference's channels==1 path
    float* out = (float*)d_out;
    const int B = in_sizes[0] / (H * W);
    const long long Nper = (long long)out_size / 3;  // elements per output array
    dim3 grid((OW + TILE - 1) / TILE, (OH + TILE - 1) / TILE, B);
    yiq_gngc_fused<<<grid, dim3(256), 0, stream>>>(x, y, out, Nper);
}